// Round 9
// baseline (716.524 us; speedup 1.0000x reference)
//
#include <hip/hip_runtime.h>

typedef float v2f __attribute__((ext_vector_type(2)));
typedef float v4f __attribute__((ext_vector_type(4)));
typedef float f32x4 __attribute__((ext_vector_type(4)));
typedef short bfrag __attribute__((ext_vector_type(8)));   // 8 bf16 bit-patterns

#define N_IN   131072
#define K_EMB  1024
#define D_EMB  64
#define QUANT_OFF 1
#define PERP_OFF  (1 + N_IN * D_EMB)      /* 8388609 */
#define ENC_OFF   (PERP_OFF + 1)          /* 8388610: %16==8 -> float2 stores only */

// R17: R16's coalesced-fragment MFMA filter, 32 samples/wave (2 row-groups).
// R16 post-mortem: k_main2 ~300us = scan L2 traffic (2 full 256KB B-stream
// reads x 8192 waves = 4GB ~ 120us) + store tail (~112us HBM) + overlap loss.
// B-stream cost is amortized over samples/wave -> doubling samples halves the
// scan's L2 traffic. Score math bit-identical to R16 -> ids unchanged.
__device__ __align__(16) unsigned int g_Ebf2[K_EMB * D_EMB / 2]; // frag order
__device__ float g_se[K_EMB];             // ||e_c|| = sqrtf(2*hn), precomputed

// ws layout (4-byte units): [0..1023] counts (u32), [1024] loss (f32),
// [2048..3071] half squared norms (f32).

__device__ __forceinline__ unsigned short f2bf(float f) {   // RNE fp32->bf16
  unsigned u = __float_as_uint(f);
  unsigned r = (u + 0x7FFFu + ((u >> 16) & 1u)) >> 16;
  return (unsigned short)r;
}

__global__ __launch_bounds__(256) void k_prep(const float* __restrict__ emb,
                                              float* __restrict__ ws) {
  int k = blockIdx.x * 256 + threadIdx.x;  // grid=4 -> k in [0,1024)
  ((unsigned int*)ws)[k] = 0u;             // zero counts (re-poison safe)
  if (k == 0) ws[1024] = 0.0f;
  const float* e = emb + (size_t)k * D_EMB;
  unsigned int row[32];
  double s = 0.0;
  unsigned int cur = 0;
  #pragma unroll
  for (int d = 0; d < D_EMB; ++d) {        // EXACT same h chain as R13/R16
    float v = e[d];
    s += (double)v * (double)v;
    if (d & 1) row[d >> 1] = cur | ((unsigned int)f2bf(v) << 16);
    else       cur = (unsigned int)f2bf(v);
  }
  float hn = (float)(0.5 * s);
  ws[2048 + k] = hn;
  g_se[k] = sqrtf(hn + hn);

  // fragment order (identical to R16): entry (nt=k>>4, lane=g*16+(k&15)):
  unsigned int* base = g_Ebf2 + ((size_t)(k >> 4) * 64 + (k & 15)) * 8;
  #pragma unroll
  for (int g = 0; g < 4; ++g) {
    unsigned int* p = base + (size_t)g * 16 * 8;
    p[0] = row[2*g];      p[1] = row[2*g + 1];
    p[2] = row[8 + 2*g];  p[3] = row[9 + 2*g];
    p[4] = row[16 + 2*g]; p[5] = row[17 + 2*g];
    p[6] = row[24 + 2*g]; p[7] = row[25 + 2*g];
  }
}

#define EPS_MUL  0.015625f    /* 2^-6: 2x the rigorous 2u=2^-7 bf16 bound */
#define ABS_EPS  3e-3f        /* covers fp32 accumulation-order differences */
#define CAND_CAP 192

__global__ __launch_bounds__(256, 4) void k_main2(const float* __restrict__ xg,
                                                  const float* __restrict__ emb,
                                                  float* __restrict__ out,
                                                  float* __restrict__ ws) {
  __shared__ int candList[4][CAND_CAP];
  __shared__ int candCnt[4];

  const int t  = threadIdx.x;
  const int w  = t >> 6;                    // wave in block
  const int L  = t & 63;                    // lane
  const int m0 = blockIdx.x * 128 + w * 32; // wave's 32 samples (2 groups)
  const int mA = L & 15;                    // A-row within group
  const int kq = L >> 4;                    // k-quad group

  if (L == 0) candCnt[w] = 0;

  // ---- A fragments per group: fp32 x -> bf16 (RNE); ||x||^2 for margins ----
  bfrag aF[2][2];
  float exmul[2][4];
  #pragma unroll
  for (int g = 0; g < 2; ++g) {
    const float* xr = xg + (size_t)(m0 + g * 16 + mA) * D_EMB;
    v4f c0 = *(const v4f*)(xr + kq * 4);
    v4f c1 = *(const v4f*)(xr + 16 + kq * 4);
    v4f c2 = *(const v4f*)(xr + 32 + kq * 4);
    v4f c3 = *(const v4f*)(xr + 48 + kq * 4);
    float xn2 = 0.f;
    #pragma unroll
    for (int i = 0; i < 4; ++i)
      xn2 += c0[i]*c0[i] + c1[i]*c1[i] + c2[i]*c2[i] + c3[i]*c3[i];
    xn2 += __shfl_xor(xn2, 16, 64);
    xn2 += __shfl_xor(xn2, 32, 64);        // ||x_{g*16+mA}||^2
    #pragma unroll
    for (int i = 0; i < 4; ++i) {
      aF[g][0][i]     = (short)f2bf(c0[i]);  aF[g][0][4 + i] = (short)f2bf(c1[i]);
      aF[g][1][i]     = (short)f2bf(c2[i]);  aF[g][1][4 + i] = (short)f2bf(c3[i]);
    }
    #pragma unroll
    for (int r = 0; r < 4; ++r)
      exmul[g][r] = EPS_MUL * sqrtf(__shfl(xn2, kq * 4 + r, 64));
  }

  // coalesced B stream: lane L's fragment pair at step nt = uint4 idx nt*128+L*2
  const uint4* bp    = ((const uint4*)g_Ebf2) + (size_t)L * 2;
  const float* hbase = ws + 2048 + (L & 15);
  const float* sbase = g_se + (L & 15);

#define STEP1(B0u,B1u,HN,SE)                                                  \
  { union { uint4 u; bfrag v; } ub0_, ub1_; ub0_.u = (B0u); ub1_.u = (B1u);   \
    _Pragma("unroll")                                                         \
    for (int g = 0; g < 2; ++g) {                                             \
      f32x4 d = {0.f, 0.f, 0.f, 0.f};                                         \
      d = __builtin_amdgcn_mfma_f32_16x16x32_bf16(aF[g][0], ub0_.v, d, 0,0,0);\
      d = __builtin_amdgcn_mfma_f32_16x16x32_bf16(aF[g][1], ub1_.v, d, 0,0,0);\
      _Pragma("unroll")                                                       \
      for (int r = 0; r < 4; ++r)                                             \
        U[g][r] = fminf(U[g][r], fmaf(exmul[g][r], (SE), ((HN) - d[r]) + ABS_EPS)); } }

#define STEP2(B0u,B1u,HN,SE,NT)                                               \
  { union { uint4 u; bfrag v; } ub0_, ub1_; ub0_.u = (B0u); ub1_.u = (B1u);   \
    _Pragma("unroll")                                                         \
    for (int g = 0; g < 2; ++g) {                                             \
      f32x4 d = {0.f, 0.f, 0.f, 0.f};                                         \
      d = __builtin_amdgcn_mfma_f32_16x16x32_bf16(aF[g][0], ub0_.v, d, 0,0,0);\
      d = __builtin_amdgcn_mfma_f32_16x16x32_bf16(aF[g][1], ub1_.v, d, 0,0,0);\
      _Pragma("unroll")                                                       \
      for (int r = 0; r < 4; ++r) {                                           \
        float sc  = (HN) - d[r];                                              \
        float eps = fmaf(exmul[g][r], (SE), ABS_EPS);                         \
        if (sc - eps <= U[g][r]) {                                            \
          int idx = atomicAdd(&candCnt[w], 1);                                \
          if (idx < CAND_CAP)                                                 \
            candList[w][idx] = ((g * 16 + kq * 4 + r) << 10)                  \
                               | ((NT) * 16 + (L & 15));                      \
        } } } }

  // ---- pass 1: per-lane slice mins (ping-pong prefetch) ----
  float U[2][4];
  #pragma unroll
  for (int g = 0; g < 2; ++g)
    #pragma unroll
    for (int r = 0; r < 4; ++r) U[g][r] = 3.4e38f;
  {
    uint4 cB0 = bp[0], cB1 = bp[1];
    float cH = hbase[0], cS = sbase[0];
    uint4 nB0, nB1; float nH, nS;
    #pragma unroll 1
    for (int k2 = 0; k2 < 32; ++k2) {
      const int nt = 2 * k2;
      nB0 = bp[(size_t)(nt + 1) * 128];
      nB1 = bp[(size_t)(nt + 1) * 128 + 1];
      nH  = hbase[(nt + 1) * 16];
      nS  = sbase[(nt + 1) * 16];
      STEP1(cB0, cB1, cH, cS)
      const int kn = (k2 < 31) ? (nt + 2) : 63;   // clamped dummy last iter
      cB0 = bp[(size_t)kn * 128];
      cB1 = bp[(size_t)kn * 128 + 1];
      cH  = hbase[kn * 16];
      cS  = sbase[kn * 16];
      STEP1(nB0, nB1, nH, nS)
    }
  }

  // reduce U across the 16 column lanes (rows live within this kq group)
  #pragma unroll
  for (int g = 0; g < 2; ++g)
    #pragma unroll
    for (int r = 0; r < 4; ++r) {
      #pragma unroll
      for (int off = 1; off < 16; off <<= 1)
        U[g][r] = fminf(U[g][r], __shfl_xor(U[g][r], off, 64));
    }

  // ---- pass 2: collect candidates {c : approx_sc - eps_c <= U} ----
  {
    uint4 cB0 = bp[0], cB1 = bp[1];
    float cH = hbase[0], cS = sbase[0];
    uint4 nB0, nB1; float nH, nS;
    #pragma unroll 1
    for (int k2 = 0; k2 < 32; ++k2) {
      const int nt = 2 * k2;
      nB0 = bp[(size_t)(nt + 1) * 128];
      nB1 = bp[(size_t)(nt + 1) * 128 + 1];
      nH  = hbase[(nt + 1) * 16];
      nS  = sbase[(nt + 1) * 16];
      STEP2(cB0, cB1, cH, cS, nt)
      const int kn = (k2 < 31) ? (nt + 2) : 63;
      cB0 = bp[(size_t)kn * 128];
      cB1 = bp[(size_t)kn * 128 + 1];
      cH  = hbase[kn * 16];
      cS  = sbase[kn * 16];
      STEP2(nB0, nB1, nH, nS, nt + 1)
    }
  }

  // ---- exact fp32 recheck; lane s ends up owning sample s's argmin (mi) ----
  int cnt = candCnt[w];                    // same-wave DS order: appends done
  float mb = 3.4e38f; int mi = K_EMB;

  if (cnt > CAND_CAP) {                    // overflow fallback (P~0): full scan
    #pragma unroll 1
    for (int s = 0; s < 32; ++s) {
      const float* xrr = xg + (size_t)(m0 + s) * D_EMB;
      float fb = 3.4e38f; int fi = 0;
      #pragma unroll 1
      for (int j = 0; j < 16; ++j) {
        int c = L * 16 + j;                // ascending within lane
        const float* er = emb + (size_t)c * D_EMB;
        float dot = 0.f;
        #pragma unroll 1
        for (int k = 0; k < 64; k += 4) {  // v4f loads, fmaf order preserved
          v4f xv = *(const v4f*)(xrr + k);
          v4f ev = *(const v4f*)(er + k);
          dot = fmaf(xv.x, ev.x, dot); dot = fmaf(xv.y, ev.y, dot);
          dot = fmaf(xv.z, ev.z, dot); dot = fmaf(xv.w, ev.w, dot);
        }
        float sc = ws[2048 + c] - dot;
        bool lt = sc < fb;
        fb = lt ? sc : fb; fi = lt ? c : fi;
      }
      #pragma unroll
      for (int i = 0; i < 6; ++i) {
        int off = 32 >> i;
        float ob = __shfl_xor(fb, off, 64);
        int   oi = __shfl_xor(fi, off, 64);
        bool tk = (ob < fb) || (ob == fb && oi < fi);
        fb = tk ? ob : fb; fi = tk ? oi : fi;
      }
      if (L == s) mi = fi;
    }
  } else {
    // lane j evaluates candidates j, j+64, j+128 (exact fp32 chain)
    float sc[3]; int mc[3], cc[3];
    #pragma unroll
    for (int j = 0; j < 3; ++j) { sc[j] = 3.4e38f; mc[j] = -1; cc[j] = 0; }
    #pragma unroll
    for (int j = 0; j < 3; ++j) {
      if (L + 64 * j < cnt) {
        int e = candList[w][L + 64 * j];
        mc[j] = e >> 10; cc[j] = e & 1023;
        const float* xrr = xg + (size_t)(m0 + mc[j]) * D_EMB;
        const float* err = emb + (size_t)cc[j] * D_EMB;
        float dot = 0.f;
        #pragma unroll
        for (int k = 0; k < 64; k += 4) {
          v4f xv = *(const v4f*)(xrr + k);
          v4f ev = *(const v4f*)(err + k);
          dot = fmaf(xv.x, ev.x, dot); dot = fmaf(xv.y, ev.y, dot);
          dot = fmaf(xv.z, ev.z, dot); dot = fmaf(xv.w, ev.w, dot);
        }
        sc[j] = ws[2048 + cc[j]] - dot;
      }
    }
    // per-sample (score, lowest idx) fold: lane s (s<32) tracks sample s
    #pragma unroll 1
    for (int i = 0; i < cnt; ++i) {
      int src = i & 63;
      float s_; int m_, c_;
      if (i < 64)       { s_ = __shfl(sc[0], src, 64); m_ = __shfl(mc[0], src, 64); c_ = __shfl(cc[0], src, 64); }
      else if (i < 128) { s_ = __shfl(sc[1], src, 64); m_ = __shfl(mc[1], src, 64); c_ = __shfl(cc[1], src, 64); }
      else              { s_ = __shfl(sc[2], src, 64); m_ = __shfl(mc[2], src, 64); c_ = __shfl(cc[2], src, 64); }
      if (m_ == L) {
        bool tk = (s_ < mb) || (s_ == mb && c_ < mi);
        mb = tk ? s_ : mb; mi = tk ? c_ : mi;
      }
    }
  }

  // ---- store phases (R13 pattern, 32 rows/wave) ----
  if (L < 32) atomicAdd((unsigned int*)ws + mi, 1u);   // lane s owns sample s

  float lsum = 0.0f;
  #pragma unroll 4
  for (int s = 0; s < 32; ++s) {
    int hit = __shfl(mi, s, 64);
    float xv = xg[(size_t)(m0 + s) * D_EMB + L];
    float ev = emb[(size_t)hit * D_EMB + L];
    float dx = ev - xv;
    lsum = fmaf(dx, dx, lsum);
    __builtin_nontemporal_store(xv + dx,
        out + QUANT_OFF + (size_t)(m0 + s) * D_EMB + L);
  }
  #pragma unroll
  for (int i = 0; i < 6; ++i) lsum += __shfl_xor(lsum, 32 >> i, 64);
  if (L == 0) atomicAdd(ws + 1024, lsum);

  v2f* eb = (v2f*)(out + ENC_OFF);
  #pragma unroll 4
  for (int s = 0; s < 32; ++s) {
    int hit = __shfl(mi, s, 64);
    int hc  = hit >> 1;
    v2f one; one.x = (hit & 1) ? 0.0f : 1.0f; one.y = (hit & 1) ? 1.0f : 0.0f;
    v2f zer; zer.x = 0.0f; zer.y = 0.0f;
    v2f* rowp = eb + (size_t)(m0 + s) * 512;
    #pragma unroll
    for (int q = 0; q < 8; ++q)
      __builtin_nontemporal_store((hc == L + 64 * q) ? one : zer,
                                  rowp + L + 64 * q);
  }
}

__global__ __launch_bounds__(256) void k_fin(float* __restrict__ out,
                                             const float* __restrict__ ws) {
  __shared__ float red[256];
  const unsigned int* counts = (const unsigned int*)ws;
  int t = threadIdx.x;
  float s = 0.0f;
  #pragma unroll
  for (int i = 0; i < 4; ++i) {
    float p = (float)counts[t + i * 256] * (1.0f / (float)N_IN);
    s += p * __logf(p + 1e-10f);
  }
  red[t] = s;
  __syncthreads();
  #pragma unroll
  for (int off = 128; off > 0; off >>= 1) {
    if (t < off) red[t] += red[t + off];
    __syncthreads();
  }
  if (t == 0) {
    out[PERP_OFF] = __expf(-red[0]);
    out[0] = 0.25f * ws[1024] * (1.0f / (float)(N_IN * D_EMB));
  }
}

extern "C" void kernel_launch(void* const* d_in, const int* in_sizes, int n_in,
                              void* d_out, int out_size, void* d_ws, size_t ws_size,
                              hipStream_t stream) {
  (void)in_sizes; (void)n_in; (void)out_size; (void)ws_size;
  const float* x   = (const float*)d_in[0];
  const float* emb = (const float*)d_in[1];
  float* out = (float*)d_out;
  float* ws  = (float*)d_ws;

  hipLaunchKernelGGL(k_prep,  dim3(4),          dim3(256), 0, stream, emb, ws);
  hipLaunchKernelGGL(k_main2, dim3(N_IN / 128), dim3(256), 0, stream, x, emb, out, ws);
  hipLaunchKernelGGL(k_fin,   dim3(1),          dim3(256), 0, stream, out, ws);
}

// Round 10
// 660.348 us; speedup vs baseline: 1.0851x; 1.0851x over previous
//
#include <hip/hip_runtime.h>

typedef float v2f __attribute__((ext_vector_type(2)));
typedef float v4f __attribute__((ext_vector_type(4)));
typedef float f32x4 __attribute__((ext_vector_type(4)));
typedef short bfrag __attribute__((ext_vector_type(8)));   // 8 bf16 bit-patterns

#define N_IN   131072
#define K_EMB  1024
#define D_EMB  64
#define QUANT_OFF 1
#define PERP_OFF  (1 + N_IN * D_EMB)      /* 8388609 */
#define ENC_OFF   (PERP_OFF + 1)          /* 8388610: %16==8 -> float2 stores only */

// R19: R16 verbatim (proven 670us, absmax 0) + 4-deep prefetch in the scan.
// R17 post-mortem: halving L2 traffic REGRESSED -> scan is L2-LATENCY bound,
// not BW bound (1-step ping-pong = ~50cy cover vs ~200cy L2 latency, at only
// ~4 waves/SIMD). Fix: 4 named prefetch slots (no dyn indexing, rule #20),
// consume-then-reissue 4 steps ahead. All math byte-identical to R16.
__device__ __align__(16) unsigned int g_Ebf2[K_EMB * D_EMB / 2]; // frag order
__device__ float g_se[K_EMB];             // ||e_c|| = sqrtf(2*hn), precomputed

// ws layout (4-byte units): [0..1023] counts (u32), [1024] loss (f32),
// [2048..3071] half squared norms (f32).

__device__ __forceinline__ unsigned short f2bf(float f) {   // RNE fp32->bf16
  unsigned u = __float_as_uint(f);
  unsigned r = (u + 0x7FFFu + ((u >> 16) & 1u)) >> 16;
  return (unsigned short)r;
}

__global__ __launch_bounds__(256) void k_prep(const float* __restrict__ emb,
                                              float* __restrict__ ws) {
  int k = blockIdx.x * 256 + threadIdx.x;  // grid=4 -> k in [0,1024)
  ((unsigned int*)ws)[k] = 0u;             // zero counts (re-poison safe)
  if (k == 0) ws[1024] = 0.0f;
  const float* e = emb + (size_t)k * D_EMB;
  unsigned int row[32];
  double s = 0.0;
  unsigned int cur = 0;
  #pragma unroll
  for (int d = 0; d < D_EMB; ++d) {        // EXACT same h chain as R13/R16
    float v = e[d];
    s += (double)v * (double)v;
    if (d & 1) row[d >> 1] = cur | ((unsigned int)f2bf(v) << 16);
    else       cur = (unsigned int)f2bf(v);
  }
  float hn = (float)(0.5 * s);
  ws[2048 + k] = hn;
  g_se[k] = sqrtf(hn + hn);

  // fragment order (identical to R16): entry (nt=k>>4, lane=g*16+(k&15)):
  unsigned int* base = g_Ebf2 + ((size_t)(k >> 4) * 64 + (k & 15)) * 8;
  #pragma unroll
  for (int g = 0; g < 4; ++g) {
    unsigned int* p = base + (size_t)g * 16 * 8;
    p[0] = row[2*g];      p[1] = row[2*g + 1];
    p[2] = row[8 + 2*g];  p[3] = row[9 + 2*g];
    p[4] = row[16 + 2*g]; p[5] = row[17 + 2*g];
    p[6] = row[24 + 2*g]; p[7] = row[25 + 2*g];
  }
}

#define EPS_MUL  0.015625f    /* 2^-6: 2x the rigorous 2u=2^-7 bf16 bound */
#define ABS_EPS  3e-3f        /* covers fp32 accumulation-order differences */
#define CAND_CAP 128

__global__ __launch_bounds__(256, 4) void k_main2(const float* __restrict__ xg,
                                                  const float* __restrict__ emb,
                                                  float* __restrict__ out,
                                                  float* __restrict__ ws) {
  __shared__ int candList[4][CAND_CAP];
  __shared__ int candCnt[4];

  const int t  = threadIdx.x;
  const int w  = t >> 6;                   // wave in block
  const int L  = t & 63;                   // lane
  const int m0 = blockIdx.x * 64 + w * 16; // wave's 16 samples
  const int mA = L & 15;                   // A-row this lane supplies
  const int kq = L >> 4;                   // k-quad group

  if (L == 0) candCnt[w] = 0;

  // ---- A fragments: fp32 x -> bf16 (RNE); also ||x||^2 partials ----
  const float* xr = xg + (size_t)(m0 + mA) * D_EMB;
  v4f c0 = *(const v4f*)(xr + kq * 4);
  v4f c1 = *(const v4f*)(xr + 16 + kq * 4);
  v4f c2 = *(const v4f*)(xr + 32 + kq * 4);
  v4f c3 = *(const v4f*)(xr + 48 + kq * 4);
  float xn2 = 0.f;
  #pragma unroll
  for (int i = 0; i < 4; ++i)
    xn2 += c0[i]*c0[i] + c1[i]*c1[i] + c2[i]*c2[i] + c3[i]*c3[i];
  xn2 += __shfl_xor(xn2, 16, 64);
  xn2 += __shfl_xor(xn2, 32, 64);          // ||x_{mA}||^2 (margin only)

  bfrag aF0, aF1;
  #pragma unroll
  for (int i = 0; i < 4; ++i) {
    aF0[i]     = (short)f2bf(c0[i]);  aF0[4 + i] = (short)f2bf(c1[i]);
    aF1[i]     = (short)f2bf(c2[i]);  aF1[4 + i] = (short)f2bf(c3[i]);
  }

  // output rows of mfma are samples kq*4+r -> eps multiplier per r
  float exmul[4];
  #pragma unroll
  for (int r = 0; r < 4; ++r)
    exmul[r] = EPS_MUL * sqrtf(__shfl(xn2, kq * 4 + r, 64));

  // coalesced B stream: lane L's fragment pair at step nt = uint4 idx nt*128+L*2
  const uint4* bp    = ((const uint4*)g_Ebf2) + (size_t)L * 2;
  const float* hbase = ws + 2048 + (L & 15);
  const float* sbase = g_se + (L & 15);

#define STEP1(B0u,B1u,HN,SE)                                                 \
  { union { uint4 u; bfrag v; } ub0_, ub1_; ub0_.u = (B0u); ub1_.u = (B1u);  \
    f32x4 d = {0.f, 0.f, 0.f, 0.f};                                          \
    d = __builtin_amdgcn_mfma_f32_16x16x32_bf16(aF0, ub0_.v, d, 0, 0, 0);    \
    d = __builtin_amdgcn_mfma_f32_16x16x32_bf16(aF1, ub1_.v, d, 0, 0, 0);    \
    _Pragma("unroll")                                                        \
    for (int r = 0; r < 4; ++r)                                              \
      U[r] = fminf(U[r], fmaf(exmul[r], (SE), ((HN) - d[r]) + ABS_EPS)); }

#define STEP2(B0u,B1u,HN,SE,NT)                                              \
  { union { uint4 u; bfrag v; } ub0_, ub1_; ub0_.u = (B0u); ub1_.u = (B1u);  \
    f32x4 d = {0.f, 0.f, 0.f, 0.f};                                          \
    d = __builtin_amdgcn_mfma_f32_16x16x32_bf16(aF0, ub0_.v, d, 0, 0, 0);    \
    d = __builtin_amdgcn_mfma_f32_16x16x32_bf16(aF1, ub1_.v, d, 0, 0, 0);    \
    _Pragma("unroll")                                                        \
    for (int r = 0; r < 4; ++r) {                                            \
      float sc  = (HN) - d[r];                                               \
      float eps = fmaf(exmul[r], (SE), ABS_EPS);                             \
      if (sc - eps <= U[r]) {                                                \
        int idx = atomicAdd(&candCnt[w], 1);                                 \
        if (idx < CAND_CAP)                                                  \
          candList[w][idx] = ((kq * 4 + r) << 10) | ((NT) * 16 + (L & 15));  \
      } } }

// 4-deep prefetch slot load (step index S_ clamped by caller)
#define PF(B0_,B1_,H_,S_,IDX)                                                \
  { B0_ = bp[(size_t)(IDX) * 128]; B1_ = bp[(size_t)(IDX) * 128 + 1];        \
    H_  = hbase[(IDX) * 16];       S_  = sbase[(IDX) * 16]; }

  // ---- pass 1: U[r] = min over this lane's slice (4-deep pipeline) ----
  float U[4] = {3.4e38f, 3.4e38f, 3.4e38f, 3.4e38f};
  {
    uint4 b0A, b1A, b0B, b1B, b0C, b1C, b0D, b1D;
    float hA, sA, hB, sB, hC, sC, hD, sD;
    PF(b0A, b1A, hA, sA, 0) PF(b0B, b1B, hB, sB, 1)
    PF(b0C, b1C, hC, sC, 2) PF(b0D, b1D, hD, sD, 3)
    #pragma unroll 1
    for (int q = 0; q < 16; ++q) {
      const int nb = 4 * q;
      const int pA = (nb + 4 < 64) ? nb + 4 : 63;   // clamped dummies at tail
      const int pB = (nb + 5 < 64) ? nb + 5 : 63;
      const int pC = (nb + 6 < 64) ? nb + 6 : 63;
      const int pD = (nb + 7 < 64) ? nb + 7 : 63;
      STEP1(b0A, b1A, hA, sA)  PF(b0A, b1A, hA, sA, pA)
      STEP1(b0B, b1B, hB, sB)  PF(b0B, b1B, hB, sB, pB)
      STEP1(b0C, b1C, hC, sC)  PF(b0C, b1C, hC, sC, pC)
      STEP1(b0D, b1D, hD, sD)  PF(b0D, b1D, hD, sD, pD)
    }
  }

  // reduce U across the 16 column lanes (rows live within this kq group)
  #pragma unroll
  for (int r = 0; r < 4; ++r) {
    #pragma unroll
    for (int off = 1; off < 16; off <<= 1)
      U[r] = fminf(U[r], __shfl_xor(U[r], off, 64));
  }

  // ---- pass 2: collect candidates {c : approx_sc - eps_c <= U} ----
  {
    uint4 b0A, b1A, b0B, b1B, b0C, b1C, b0D, b1D;
    float hA, sA, hB, sB, hC, sC, hD, sD;
    PF(b0A, b1A, hA, sA, 0) PF(b0B, b1B, hB, sB, 1)
    PF(b0C, b1C, hC, sC, 2) PF(b0D, b1D, hD, sD, 3)
    #pragma unroll 1
    for (int q = 0; q < 16; ++q) {
      const int nb = 4 * q;
      const int pA = (nb + 4 < 64) ? nb + 4 : 63;
      const int pB = (nb + 5 < 64) ? nb + 5 : 63;
      const int pC = (nb + 6 < 64) ? nb + 6 : 63;
      const int pD = (nb + 7 < 64) ? nb + 7 : 63;
      STEP2(b0A, b1A, hA, sA, nb)      PF(b0A, b1A, hA, sA, pA)
      STEP2(b0B, b1B, hB, sB, nb + 1)  PF(b0B, b1B, hB, sB, pB)
      STEP2(b0C, b1C, hC, sC, nb + 2)  PF(b0C, b1C, hC, sC, pC)
      STEP2(b0D, b1D, hD, sD, nb + 3)  PF(b0D, b1D, hD, sD, pD)
    }
  }

  // ---- exact fp32 recheck (same chain/h/tie rule as R13 -> identical ids) --
  int cnt = candCnt[w];                    // same-wave DS order: appends done
  int bidx[16];

  if (cnt > CAND_CAP) {                    // overflow fallback (P~0): full scan
    #pragma unroll 1
    for (int s = 0; s < 16; ++s) {
      const float* xrr = xg + (size_t)(m0 + s) * D_EMB;
      float fb = 3.4e38f; int fi = 0;
      #pragma unroll 1
      for (int j = 0; j < 16; ++j) {
        int c = L * 16 + j;                // ascending within lane
        const float* er = emb + (size_t)c * D_EMB;
        float dot = 0.f;
        #pragma unroll 1
        for (int k = 0; k < 64; k += 4) {  // v4f loads, fmaf order preserved
          v4f xv = *(const v4f*)(xrr + k);
          v4f ev = *(const v4f*)(er + k);
          dot = fmaf(xv.x, ev.x, dot); dot = fmaf(xv.y, ev.y, dot);
          dot = fmaf(xv.z, ev.z, dot); dot = fmaf(xv.w, ev.w, dot);
        }
        float sc = ws[2048 + c] - dot;
        bool lt = sc < fb;
        fb = lt ? sc : fb; fi = lt ? c : fi;
      }
      #pragma unroll
      for (int i = 0; i < 6; ++i) {
        int off = 32 >> i;
        float ob = __shfl_xor(fb, off, 64);
        int   oi = __shfl_xor(fi, off, 64);
        bool tk = (ob < fb) || (ob == fb && oi < fi);
        fb = tk ? ob : fb; fi = tk ? oi : fi;
      }
      bidx[s] = fi;
    }
  } else {
    // lane j evaluates candidates j and j+64 (exact fp32 chain, k ascending)
    float sc0 = 3.4e38f, sc1 = 3.4e38f;
    int mc0 = -1, cc0 = 0, mc1 = -1, cc1 = 0;
    if (L < cnt) {
      int e = candList[w][L]; mc0 = e >> 10; cc0 = e & 1023;
      const float* xrr = xg + (size_t)(m0 + mc0) * D_EMB;
      const float* err = emb + (size_t)cc0 * D_EMB;
      float dot = 0.f;
      #pragma unroll
      for (int k = 0; k < 64; k += 4) {
        v4f xv = *(const v4f*)(xrr + k);
        v4f ev = *(const v4f*)(err + k);
        dot = fmaf(xv.x, ev.x, dot); dot = fmaf(xv.y, ev.y, dot);
        dot = fmaf(xv.z, ev.z, dot); dot = fmaf(xv.w, ev.w, dot);
      }
      sc0 = ws[2048 + cc0] - dot;
    }
    if (L + 64 < cnt) {
      int e = candList[w][L + 64]; mc1 = e >> 10; cc1 = e & 1023;
      const float* xrr = xg + (size_t)(m0 + mc1) * D_EMB;
      const float* err = emb + (size_t)cc1 * D_EMB;
      float dot = 0.f;
      #pragma unroll
      for (int k = 0; k < 64; k += 4) {
        v4f xv = *(const v4f*)(xrr + k);
        v4f ev = *(const v4f*)(err + k);
        dot = fmaf(xv.x, ev.x, dot); dot = fmaf(xv.y, ev.y, dot);
        dot = fmaf(xv.z, ev.z, dot); dot = fmaf(xv.w, ev.w, dot);
      }
      sc1 = ws[2048 + cc1] - dot;
    }
    // per-sample (score, lowest idx) fold: lane s tracks sample s
    float mb = 3.4e38f; int mi = K_EMB;
    #pragma unroll 1
    for (int i = 0; i < cnt; ++i) {
      int src = i & 63;
      float s_; int m_, c_;
      if (i < 64) { s_ = __shfl(sc0, src, 64); m_ = __shfl(mc0, src, 64); c_ = __shfl(cc0, src, 64); }
      else        { s_ = __shfl(sc1, src, 64); m_ = __shfl(mc1, src, 64); c_ = __shfl(cc1, src, 64); }
      if (m_ == L) {
        bool tk = (s_ < mb) || (s_ == mb && c_ < mi);
        mb = tk ? s_ : mb; mi = tk ? c_ : mi;
      }
    }
    #pragma unroll
    for (int s = 0; s < 16; ++s) bidx[s] = __shfl(mi, s, 64);
  }

  // ---- store phases: R13 verbatim ----
  #pragma unroll
  for (int s = 0; s < 16; ++s)
    if (L == s) atomicAdd((unsigned int*)ws + bidx[s], 1u);

  float lsum = 0.0f;
  #pragma unroll
  for (int s = 0; s < 16; ++s) {
    float xv = xg[(size_t)(m0 + s) * D_EMB + L];
    float ev = emb[(size_t)bidx[s] * D_EMB + L];
    float dx = ev - xv;
    lsum = fmaf(dx, dx, lsum);
    __builtin_nontemporal_store(xv + dx,
        out + QUANT_OFF + (size_t)(m0 + s) * D_EMB + L);
  }
  #pragma unroll
  for (int i = 0; i < 6; ++i) lsum += __shfl_xor(lsum, 32 >> i, 64);
  if (L == 0) atomicAdd(ws + 1024, lsum);

  v2f* eb = (v2f*)(out + ENC_OFF);
  #pragma unroll
  for (int s = 0; s < 16; ++s) {
    int hit = bidx[s];
    int hc  = hit >> 1;
    v2f one; one.x = (hit & 1) ? 0.0f : 1.0f; one.y = (hit & 1) ? 1.0f : 0.0f;
    v2f zer; zer.x = 0.0f; zer.y = 0.0f;
    v2f* rowp = eb + (size_t)(m0 + s) * 512;
    #pragma unroll
    for (int q = 0; q < 8; ++q)
      __builtin_nontemporal_store((hc == L + 64 * q) ? one : zer,
                                  rowp + L + 64 * q);
  }
}

__global__ __launch_bounds__(256) void k_fin(float* __restrict__ out,
                                             const float* __restrict__ ws) {
  __shared__ float red[256];
  const unsigned int* counts = (const unsigned int*)ws;
  int t = threadIdx.x;
  float s = 0.0f;
  #pragma unroll
  for (int i = 0; i < 4; ++i) {
    float p = (float)counts[t + i * 256] * (1.0f / (float)N_IN);
    s += p * __logf(p + 1e-10f);
  }
  red[t] = s;
  __syncthreads();
  #pragma unroll
  for (int off = 128; off > 0; off >>= 1) {
    if (t < off) red[t] += red[t + off];
    __syncthreads();
  }
  if (t == 0) {
    out[PERP_OFF] = __expf(-red[0]);
    out[0] = 0.25f * ws[1024] * (1.0f / (float)(N_IN * D_EMB));
  }
}

extern "C" void kernel_launch(void* const* d_in, const int* in_sizes, int n_in,
                              void* d_out, int out_size, void* d_ws, size_t ws_size,
                              hipStream_t stream) {
  (void)in_sizes; (void)n_in; (void)out_size; (void)ws_size;
  const float* x   = (const float*)d_in[0];
  const float* emb = (const float*)d_in[1];
  float* out = (float*)d_out;
  float* ws  = (float*)d_ws;

  hipLaunchKernelGGL(k_prep,  dim3(4),         dim3(256), 0, stream, emb, ws);
  hipLaunchKernelGGL(k_main2, dim3(N_IN / 64), dim3(256), 0, stream, x, emb, out, ws);
  hipLaunchKernelGGL(k_fin,   dim3(1),         dim3(256), 0, stream, out, ws);
}